// Round 1
// baseline (290.164 us; speedup 1.0000x reference)
//
#include <hip/hip_runtime.h>
#include <stdint.h>

// Problem constants: x (8,256,32,32) f32, embed_w (4096,256) f32
// M = 8192 rows (b,n), K = 4096 codes, d = 256
// out layout (floats): [0,2097152) x_q (b,c,h,w); [2097152] loss; [2097153,2105345) embed_ind as float
// ws layout: e2 f32[4096] @0; negx2 f32[8192] @16384B; cand u64[8192*32] @49152B (total ~2.05 MB)

__device__ __forceinline__ unsigned int sortable_f32(float v) {
    unsigned int u = __float_as_uint(v);
    return (u & 0x80000000u) ? ~u : (u | 0x80000000u);
}

__global__ void vq_pre(const float* __restrict__ x, const float* __restrict__ ew,
                       float* __restrict__ e2, float* __restrict__ negx2,
                       float* __restrict__ loss_cell) {
    const int blk = blockIdx.x, tid = threadIdx.x;
    if (blk == 0 && tid == 0) *loss_cell = 0.0f;
    if (blk < 16) {
        // e2[k] = sum_c ew[k][c]^2   (4096 threads, one k each)
        const int k = blk * 256 + tid;
        const float4* row = (const float4*)(ew + k * 256);
        float s = 0.0f;
#pragma unroll 8
        for (int i = 0; i < 64; ++i) {
            float4 v = row[i];
            s += v.x * v.x + v.y * v.y + v.z * v.z + v.w * v.w;
        }
        e2[k] = s;
    } else {
        // negx2[r] = -sum_c x[b][c][n]^2 ; r=(b,n), coalesced along n
        const int r = (blk - 16) * 256 + tid;
        const int b = r >> 10, n = r & 1023;
        const float* px = x + b * 262144 + n;
        float s = 0.0f;
#pragma unroll 8
        for (int c = 0; c < 256; ++c) {
            float v = px[c << 10];
            s += v * v;
        }
        negx2[r] = -s;
    }
}

// 128x128 tile fp32 distance GEMM + per-tile argmax.
// dist = (negx2[m] - e2[k]) + 2*dot  -- EXACT rounding structure of the reference
// (quantized at ulp(~256): replicating this is required for argmax index match).
__launch_bounds__(256, 4)
__global__ void vq_dist(const float* __restrict__ x, const float* __restrict__ ew,
                        const float* __restrict__ e2, const float* __restrict__ negx2,
                        unsigned long long* __restrict__ cand) {
    __shared__ float xs[32][132];   // [cc][nn], d-major, +4 pad
    __shared__ float es[32][132];   // [cc][kk]
    __shared__ float e2s[128];
    __shared__ float nx2s[128];

    const int tid = threadIdx.x;
    const int kt = blockIdx.x;      // 0..31
    const int mt = blockIdx.y;      // 0..63
    const int m0 = mt * 128, k0 = kt * 128;
    const int b = m0 >> 10, n0 = m0 & 1023;

    if (tid < 128) {
        e2s[tid]  = e2[k0 + tid];
        nx2s[tid] = negx2[m0 + tid];
    }

    float acc[8][8];
#pragma unroll
    for (int i = 0; i < 8; ++i)
#pragma unroll
        for (int j = 0; j < 8; ++j) acc[i][j] = 0.0f;

    const int tx = tid & 15, ty = tid >> 4;

    for (int ci = 0; ci < 8; ++ci) {
        const int c0 = ci * 32;
        __syncthreads();
        // stage x tile: 128 nn x 32 cc; contiguous along n in global AND LDS
#pragma unroll
        for (int it = 0; it < 4; ++it) {
            int q = tid + it * 256;            // 0..1023 float4s
            int cc = q >> 5, nn4 = q & 31;
            float4 v = *(const float4*)(x + b * 262144 + (c0 + cc) * 1024 + n0 + nn4 * 4);
            *(float4*)&xs[cc][nn4 * 4] = v;
        }
        // stage e tile with transpose: global contiguous along c, scatter to d-major LDS
#pragma unroll
        for (int it = 0; it < 4; ++it) {
            int q = tid + it * 256;
            int kk = q >> 3, c4 = q & 7;
            float4 v = *(const float4*)(ew + (k0 + kk) * 256 + c0 + c4 * 4);
            es[c4 * 4 + 0][kk] = v.x;
            es[c4 * 4 + 1][kk] = v.y;
            es[c4 * 4 + 2][kk] = v.z;
            es[c4 * 4 + 3][kk] = v.w;
        }
        __syncthreads();
#pragma unroll 8
        for (int cc = 0; cc < 32; ++cc) {
            // fragments split 4+4 (offset 64) keeps LDS bank aliasing <= 2-way
            float4 xa = *(const float4*)&xs[cc][ty * 4];
            float4 xb = *(const float4*)&xs[cc][64 + ty * 4];
            float4 ea = *(const float4*)&es[cc][tx * 4];
            float4 eb = *(const float4*)&es[cc][64 + tx * 4];
            float xf[8] = {xa.x, xa.y, xa.z, xa.w, xb.x, xb.y, xb.z, xb.w};
            float ef[8] = {ea.x, ea.y, ea.z, ea.w, eb.x, eb.y, eb.z, eb.w};
#pragma unroll
            for (int i = 0; i < 8; ++i)
#pragma unroll
                for (int j = 0; j < 8; ++j)
                    acc[i][j] += xf[i] * ef[j];
        }
    }

    // epilogue: per-row best over this block's 128 codes
    unsigned long long bestkey[8];
#pragma unroll
    for (int i = 0; i < 8; ++i) {
        const int nn = (i < 4) ? (ty * 4 + i) : (64 + ty * 4 + (i - 4));
        const float A = nx2s[nn];
        unsigned long long bk = 0ull;
#pragma unroll
        for (int j = 0; j < 8; ++j) {
            const int kk = (j < 4) ? (tx * 4 + j) : (64 + tx * 4 + (j - 4));
            // two fp32 roundings, exactly like the reference (2*dot is exact)
            float dist = (A - e2s[kk]) + 2.0f * acc[i][j];
            // key: larger dist wins; on exact fp32 tie, lower global k wins (numpy argmax)
            unsigned long long key = ((unsigned long long)sortable_f32(dist) << 32)
                                   | (unsigned long long)(unsigned int)(4095 - (k0 + kk));
            bk = (key > bk) ? key : bk;
        }
        bestkey[i] = bk;
    }
    __syncthreads();
    unsigned long long* red = (unsigned long long*)&xs[0][0]; // 128*16*8 = 16384 B fits
#pragma unroll
    for (int i = 0; i < 8; ++i) {
        const int nn = (i < 4) ? (ty * 4 + i) : (64 + ty * 4 + (i - 4));
        red[nn * 16 + tx] = bestkey[i];
    }
    __syncthreads();
    if (tid < 128) {
        unsigned long long bk = 0ull;
#pragma unroll
        for (int t = 0; t < 16; ++t) {
            unsigned long long v = red[tid * 16 + t];
            bk = (v > bk) ? v : bk;
        }
        cand[(m0 + tid) * 32 + kt] = bk;
    }
}

// final reduce + gather + transposed store + loss
__global__ void vq_out(const float* __restrict__ x, const float* __restrict__ ew,
                       const unsigned long long* __restrict__ cand,
                       float* __restrict__ out) {
    __shared__ int sidx[64];
    __shared__ float wsum[4];
    const int tid = threadIdx.x;
    const int r0 = blockIdx.x * 64;
    const int b = r0 >> 10, n0 = r0 & 1023;

    if (tid < 64) {
        const int r = r0 + tid;
        unsigned long long bk = 0ull;
#pragma unroll 8
        for (int kt = 0; kt < 32; ++kt) {
            unsigned long long v = cand[r * 32 + kt];
            bk = (v > bk) ? v : bk;
        }
        const int idx = 4095 - (int)(unsigned int)(bk & 0xFFFFFFFFull);
        sidx[tid] = idx;
        out[2097153 + r] = (float)idx;   // embed_ind as float
    }
    __syncthreads();

    const int nn = tid & 63, cq = tid >> 6;
    const int myidx = sidx[nn];
    float lsum = 0.0f;
#pragma unroll 4
    for (int cb = 0; cb < 256; cb += 4) {
        const int c = cb + cq;
        const float ve = ew[myidx * 256 + c];
        const long off = (long)b * 262144 + (c << 10) + n0 + nn;
        const float vx = x[off];
        out[off] = ve;                    // x_q forward value, (b,c,h,w) layout
        const float d = ve - vx;
        lsum += d * d;
    }
    // wave + block reduce, one atomic per block
#pragma unroll
    for (int off = 32; off > 0; off >>= 1)
        lsum += __shfl_down(lsum, off, 64);
    const int lane = tid & 63, w = tid >> 6;
    if (lane == 0) wsum[w] = lsum;
    __syncthreads();
    if (tid == 0) {
        const float s = wsum[0] + wsum[1] + wsum[2] + wsum[3];
        atomicAdd(&out[2097152], 1.25f * (s / 2097152.0f));
    }
}

extern "C" void kernel_launch(void* const* d_in, const int* in_sizes, int n_in,
                              void* d_out, int out_size, void* d_ws, size_t ws_size,
                              hipStream_t stream) {
    const float* x  = (const float*)d_in[0];
    const float* ew = (const float*)d_in[1];
    float* out = (float*)d_out;
    float* e2 = (float*)d_ws;
    float* negx2 = e2 + 4096;
    unsigned long long* cand = (unsigned long long*)((char*)d_ws + 49152);

    vq_pre<<<48, 256, 0, stream>>>(x, ew, e2, negx2, out + 2097152);
    vq_dist<<<dim3(32, 64), 256, 0, stream>>>(x, ew, e2, negx2, cand);
    vq_out<<<128, 256, 0, stream>>>(x, ew, cand, out);
}

// Round 2
// 165.717 us; speedup vs baseline: 1.7510x; 1.7510x over previous
//
#include <hip/hip_runtime.h>
#include <stdint.h>

// VectorQuantize: x (8,256,32,32) f32, embed_w (4096,256) f32
// M = 8192 rows (b,n), K = 4096 codes, d = 256
// out (floats): [0,2097152) x_q (b,c,h,w); [2097152] loss; [2097153,2105345) embed_ind
//
// Strategy: split-fp16 MFMA GEMM (h1+h2 per operand, 3 MFMAs per fp32-equiv dot,
// e scaled by 2^12 to avoid fp16 subnormal loss on e_lo; delta vs numpy ~1.5e-9
// << ulp(256)=3e-5, matching the reference's fp32 rounding grid).
// dist = fl(fl(negx2[m] - e2[k]) + acc*2^-11)  -- same two-rounding structure.
//
// Scratch: e-planes + e2/negx2/cand in ws (~4.3 MB); x-planes live in the x_q
// region of d_out (8 MB exactly) and are overwritten by vq_out at the end.

typedef _Float16 f16;
typedef f16 half8 __attribute__((ext_vector_type(8)));
typedef float f32x4 __attribute__((ext_vector_type(4)));

__device__ __forceinline__ unsigned int sortable_f32(float v) {
    unsigned int u = __float_as_uint(v);
    return (u & 0x80000000u) ? ~u : (u | 0x80000000u);
}

__device__ __forceinline__ void gload_lds16(const void* g, void* l) {
    __builtin_amdgcn_global_load_lds(
        (const __attribute__((address_space(1))) unsigned int*)g,
        (__attribute__((address_space(3))) unsigned int*)l, 16, 0, 0);
}

// ---- pre: e2, negx2 (bit-identical to the passing round-1 code), cand/loss zero ----
__global__ void vq_pre(const float* __restrict__ x, const float* __restrict__ ew,
                       float* __restrict__ e2, float* __restrict__ negx2,
                       unsigned long long* __restrict__ cand,
                       float* __restrict__ loss_cell) {
    const int blk = blockIdx.x, tid = threadIdx.x;
    if (blk == 0 && tid == 0) *loss_cell = 0.0f;
    if (blk < 32) cand[blk * 256 + tid] = 0ull;
    if (blk < 16) {
        const int k = blk * 256 + tid;
        const float4* row = (const float4*)(ew + k * 256);
        float s = 0.0f;
#pragma unroll 8
        for (int i = 0; i < 64; ++i) {
            float4 v = row[i];
            s += v.x * v.x + v.y * v.y + v.z * v.z + v.w * v.w;
        }
        e2[k] = s;
    } else {
        const int r = (blk - 16) * 256 + tid;
        const int b = r >> 10, n = r & 1023;
        const float* px = x + b * 262144 + n;
        float s = 0.0f;
#pragma unroll 8
        for (int c = 0; c < 256; ++c) {
            float v = px[c << 10];
            s += v * v;
        }
        negx2[r] = -s;
    }
}

// ---- split e (scaled by 2^12) into swizzled-tile fp16 hi/lo planes ----
// plane layout (halves): ((kt*8+ci)*128 + kk)*32 + ((g ^ (kk&3))*8) + j, d = ci*32+g*8+j
__global__ void split_e(const float* __restrict__ ew, f16* __restrict__ ehi, f16* __restrict__ elo) {
    const int t = blockIdx.x * 256 + threadIdx.x;  // 131072 = 4096 k * 32 groups
    const int k = t >> 5, g32 = t & 31;
    const float4 v0 = *(const float4*)(ew + k * 256 + g32 * 8);
    const float4 v1 = *(const float4*)(ew + k * 256 + g32 * 8 + 4);
    const float vf[8] = {v0.x, v0.y, v0.z, v0.w, v1.x, v1.y, v1.z, v1.w};
    half8 h1, h2;
#pragma unroll
    for (int j = 0; j < 8; ++j) {
        const float v = vf[j] * 4096.0f;   // exact (power of 2)
        const f16 a = (f16)v;
        const f16 b = (f16)(v - (float)a); // v-(float)a exact in fp32
        h1[j] = a; h2[j] = b;
    }
    const int kt = k >> 7, kk = k & 127, ci = g32 >> 2, g = g32 & 3;
    const long off = ((long)((kt * 8 + ci) * 128 + kk)) * 32 + ((g ^ (kk & 3)) * 8);
    *(half8*)(ehi + off) = h1;
    *(half8*)(elo + off) = h2;
}

// ---- split x (transpose (b,c,n)->(m,d)) into swizzled-tile fp16 hi/lo planes ----
__global__ void split_x(const float* __restrict__ x, f16* __restrict__ xhi, f16* __restrict__ xlo) {
    __shared__ float xs[32][132];  // [cc][nn], padded for alignment + banks
    const int tid = threadIdx.x;
    const int ci = blockIdx.x, mt = blockIdx.y;
    const int b = mt >> 3, n0 = (mt & 7) * 128, c0 = ci * 32;
#pragma unroll
    for (int it = 0; it < 4; ++it) {
        const int idx = tid + it * 256;
        const int cc = idx >> 5, nn4 = idx & 31;
        float4 v = *(const float4*)(x + b * 262144 + (c0 + cc) * 1024 + n0 + nn4 * 4);
        *(float4*)&xs[cc][nn4 * 4] = v;
    }
    __syncthreads();
#pragma unroll
    for (int it = 0; it < 2; ++it) {
        const int idx = tid + it * 256;
        const int mm = idx & 127, g = idx >> 7;
        half8 h1, h2;
#pragma unroll
        for (int j = 0; j < 8; ++j) {
            const float v = xs[g * 8 + j][mm];
            const f16 a = (f16)v;
            const f16 bb = (f16)(v - (float)a);
            h1[j] = a; h2[j] = bb;
        }
        const long off = ((long)((mt * 8 + ci) * 128 + mm)) * 32 + ((g ^ (mm & 3)) * 8);
        *(half8*)(xhi + off) = h1;
        *(half8*)(xlo + off) = h2;
    }
}

// ---- split-fp16 MFMA distance GEMM + argmax epilogue ----
// block: 128(m) x 128(k), 4 waves in 2x2, each wave 4x4 subtiles of 16x16x32 f16
__launch_bounds__(256, 2)
__global__ void vq_gemm(const f16* __restrict__ xhi, const f16* __restrict__ xlo,
                        const f16* __restrict__ ehi, const f16* __restrict__ elo,
                        const float* __restrict__ e2, const float* __restrict__ negx2,
                        unsigned long long* __restrict__ cand) {
    __shared__ __align__(16) f16 lds[16384];  // 32 KB: xhi|xlo|ehi|elo, 4096 halves each
    const int tid = threadIdx.x;
    const int kt = blockIdx.x, mt = blockIdx.y;
    const int lane = tid & 63, wave = tid >> 6;
    const int wm = wave >> 1, wk = wave & 1;
    const int col = lane & 15, quad = lane >> 4;

    f32x4 acc[4][4] = {};

    const f16* gx[2] = { xhi + (size_t)(mt * 8) * 4096, xlo + (size_t)(mt * 8) * 4096 };
    const f16* ge[2] = { ehi + (size_t)(kt * 8) * 4096, elo + (size_t)(kt * 8) * 4096 };

    int aoff[4], boff[4];
#pragma unroll
    for (int i = 0; i < 4; ++i) {
        const int m = wm * 64 + i * 16 + col;
        aoff[i] = m * 32 + ((quad ^ (m & 3)) * 8);
        const int k = wk * 64 + i * 16 + col;
        boff[i] = k * 32 + ((quad ^ (k & 3)) * 8);
    }

    for (int ci = 0; ci < 8; ++ci) {
        __syncthreads();
        const int go = ci * 4096 + tid * 8;             // halves
        char* lb = (char*)lds + (tid >> 6) * 1024;      // wave-uniform dst base
#pragma unroll
        for (int p = 0; p < 2; ++p) {
            gload_lds16(gx[p] + go,        lb + p * 8192);
            gload_lds16(gx[p] + go + 2048, lb + p * 8192 + 4096);
            gload_lds16(ge[p] + go,        lb + 16384 + p * 8192);
            gload_lds16(ge[p] + go + 2048, lb + 16384 + p * 8192 + 4096);
        }
        __syncthreads();

        half8 ahi[4], alo[4], bhi[4], blo[4];
#pragma unroll
        for (int i = 0; i < 4; ++i) {
            ahi[i] = *(const half8*)&lds[aoff[i]];
            alo[i] = *(const half8*)&lds[4096 + aoff[i]];
            bhi[i] = *(const half8*)&lds[8192 + boff[i]];
            blo[i] = *(const half8*)&lds[12288 + boff[i]];
        }
#pragma unroll
        for (int i = 0; i < 4; ++i)
#pragma unroll
            for (int j = 0; j < 4; ++j) {
                acc[i][j] = __builtin_amdgcn_mfma_f32_16x16x32_f16(ahi[i], bhi[j], acc[i][j], 0, 0, 0);
                acc[i][j] = __builtin_amdgcn_mfma_f32_16x16x32_f16(ahi[i], blo[j], acc[i][j], 0, 0, 0);
                acc[i][j] = __builtin_amdgcn_mfma_f32_16x16x32_f16(alo[i], bhi[j], acc[i][j], 0, 0, 0);
            }
    }

    // epilogue: per-row argmax keys; C layout: col(n=k)=lane&15, row(m)=quad*4+reg
    const int m0 = mt * 128 + wm * 64, k0 = kt * 128 + wk * 64;
    unsigned long long best[4][4];
#pragma unroll
    for (int i = 0; i < 4; ++i)
#pragma unroll
        for (int r = 0; r < 4; ++r) {
            const float A = negx2[m0 + i * 16 + quad * 4 + r];
            unsigned long long bk = 0ull;
#pragma unroll
            for (int j = 0; j < 4; ++j) {
                const int k = k0 + j * 16 + col;
                const float t1 = A - e2[k];                 // rounding 1 (as reference)
                const float dist = t1 + acc[i][j][r] * 0x1p-11f;  // *2^-11 exact; rounding 2
                const unsigned long long key =
                    ((unsigned long long)sortable_f32(dist) << 32)
                    | (unsigned long long)(unsigned int)(4095 - k);
                bk = key > bk ? key : bk;
            }
            best[i][r] = bk;
        }
#pragma unroll
    for (int i = 0; i < 4; ++i)
#pragma unroll
        for (int r = 0; r < 4; ++r) {
#pragma unroll
            for (int mask = 1; mask <= 8; mask <<= 1) {
                const unsigned long long o = __shfl_xor(best[i][r], mask, 64);
                if (o > best[i][r]) best[i][r] = o;
            }
            if (col == i * 4 + r)
                atomicMax(&cand[m0 + i * 16 + quad * 4 + r], best[i][r]);
        }
}

// ---- final: gather, transposed store, loss, embed_ind ----
__global__ void vq_out(const float* __restrict__ x, const float* __restrict__ ew,
                       const unsigned long long* __restrict__ cand,
                       float* __restrict__ out) {
    __shared__ int sidx[64];
    __shared__ float wsum[4];
    const int tid = threadIdx.x;
    const int r0 = blockIdx.x * 64;
    const int b = r0 >> 10, n0 = r0 & 1023;

    if (tid < 64) {
        const int r = r0 + tid;
        const unsigned long long bk = cand[r];
        const int idx = 4095 - (int)(unsigned int)(bk & 0xFFFFFFFFull);
        sidx[tid] = idx;
        out[2097153 + r] = (float)idx;
    }
    __syncthreads();

    const int nn = tid & 63, cq = tid >> 6;
    const int myidx = sidx[nn];
    float lsum = 0.0f;
#pragma unroll 4
    for (int cb = 0; cb < 256; cb += 4) {
        const int c = cb + cq;
        const float ve = ew[myidx * 256 + c];
        const long off = (long)b * 262144 + (c << 10) + n0 + nn;
        const float vx = x[off];
        out[off] = ve;
        const float d = ve - vx;
        lsum += d * d;
    }
#pragma unroll
    for (int off = 32; off > 0; off >>= 1)
        lsum += __shfl_down(lsum, off, 64);
    const int lane = tid & 63, w = tid >> 6;
    if (lane == 0) wsum[w] = lsum;
    __syncthreads();
    if (tid == 0) {
        const float s = wsum[0] + wsum[1] + wsum[2] + wsum[3];
        atomicAdd(&out[2097152], 1.25f * (s / 2097152.0f));
    }
}

extern "C" void kernel_launch(void* const* d_in, const int* in_sizes, int n_in,
                              void* d_out, int out_size, void* d_ws, size_t ws_size,
                              hipStream_t stream) {
    const float* x  = (const float*)d_in[0];
    const float* ew = (const float*)d_in[1];
    float* out = (float*)d_out;

    float* e2 = (float*)d_ws;                                        // 16 KB
    float* negx2 = e2 + 4096;                                        // 32 KB
    unsigned long long* cand = (unsigned long long*)((char*)d_ws + 49152);   // 64 KB
    f16* ehi = (f16*)((char*)d_ws + 114688);                         // 2 MB
    f16* elo = (f16*)((char*)d_ws + 114688 + 2097152);               // 2 MB
    f16* xhi = (f16*)out;                                            // 4 MB (x_q region scratch)
    f16* xlo = (f16*)(out + 1048576);                                // 4 MB

    vq_pre<<<48, 256, 0, stream>>>(x, ew, e2, negx2, cand, out + 2097152);
    split_e<<<512, 256, 0, stream>>>(ew, ehi, elo);
    split_x<<<dim3(8, 64), 256, 0, stream>>>(x, xhi, xlo);
    vq_gemm<<<dim3(32, 64), 256, 0, stream>>>(xhi, xlo, ehi, elo, e2, negx2, cand);
    vq_out<<<128, 256, 0, stream>>>(x, ew, cand, out);
}